// Round 8
// baseline (623.484 us; speedup 1.0000x reference)
//
#include <hip/hip_runtime.h>

#define N_NODES  50000
#define N_EDGES  800000
#define NSC      32
#define XD       96
#define HID      128
#define LDH      136   // h tile stride (bf16 elems), 128+8 pad
#define LDXO     100   // x_out stride (fp32 elems), 96+4 pad
#define NBLK     196   // ceil(50000/256)
#define NTILES   50000 // N_EDGES / 16
#define TPW      25    // tiles per wave: 2048 waves * 25 >= 50000

typedef __bf16 bf16x8 __attribute__((ext_vector_type(8)));
typedef float  f32x4  __attribute__((ext_vector_type(4)));
typedef unsigned short u16x8 __attribute__((ext_vector_type(8)));

__device__ __forceinline__ unsigned short f2bf(float f) {
    union { float f; unsigned int u; } v; v.f = f;
    unsigned int u = v.u;
    return (unsigned short)((u + 0x7FFFu + ((u >> 16) & 1u)) >> 16);
}

// Wave-local stage fence: order LDS ops of THIS wave (no cross-wave wait).
#define WAVE_SYNC() do { \
    asm volatile("s_waitcnt lgkmcnt(0)" ::: "memory"); \
    __builtin_amdgcn_sched_barrier(0); \
} while (0)

// ---------------------------------------------------------------------------
// Weight prep, LDS-fragment order:
//  W1R[kt*1024 + n*8 + j] = bf16(W1[(kt*8+j)*128 + n])   kt in [0,32), n in [0,128)
//  W2R[kt*768  + n*8 + j] = bf16(W2[(kt*8+j)*96  + n])   kt in [0,16), n in [0,96)
__global__ void prep_weights(const float* __restrict__ W1, const float* __restrict__ W2,
                             unsigned short* __restrict__ W1R, unsigned short* __restrict__ W2R) {
    int o = blockIdx.x * 256 + threadIdx.x;
    if (o < 32 * 128 * 8) {
        int j = o & 7, ch = o >> 3;
        int n = ch & 127, kt = ch >> 7;
        W1R[o] = f2bf(W1[(kt * 8 + j) * 128 + n]);
    }
    if (o < 16 * 96 * 8) {
        int j = o & 7, ch = o >> 3;
        int n = ch % 96, kt = ch / 96;
        W2R[o] = f2bf(W2[(kt * 8 + j) * 96 + n]);
    }
}

// ---------------------------------------------------------------------------
// CSR build: fused histogram+rank -> block scan -> top scan -> fixup -> scatter.
__global__ void rank0_kernel(const int* __restrict__ eidx, int* __restrict__ cnt,
                             int* __restrict__ pos0) {
    int e = blockIdx.x * 256 + threadIdx.x;
    if (e < N_EDGES) pos0[e] = atomicAdd(&cnt[eidx[N_EDGES + e]], 1);
}

__global__ void scan_block(const int* __restrict__ cnt, int* __restrict__ start,
                           int* __restrict__ bsum) {
    __shared__ int tmp[256];
    const int t = threadIdx.x, i = blockIdx.x * 256 + t;
    int v = (i < N_NODES) ? cnt[i] : 0;
    tmp[t] = v; __syncthreads();
    #pragma unroll
    for (int off = 1; off < 256; off <<= 1) {
        int add = (t >= off) ? tmp[t - off] : 0;
        __syncthreads();
        tmp[t] += add;
        __syncthreads();
    }
    if (i < N_NODES) start[i] = tmp[t] - v;
    if (t == 255) bsum[blockIdx.x] = tmp[255];
}

__global__ void scan_top(const int* __restrict__ bsum, int* __restrict__ boff,
                         int* __restrict__ start) {
    __shared__ int tmp[256];
    const int t = threadIdx.x;
    int v = (t < NBLK) ? bsum[t] : 0;
    tmp[t] = v; __syncthreads();
    #pragma unroll
    for (int off = 1; off < 256; off <<= 1) {
        int add = (t >= off) ? tmp[t - off] : 0;
        __syncthreads();
        tmp[t] += add;
        __syncthreads();
    }
    if (t < NBLK) boff[t] = tmp[t] - v;
    if (t == 255) start[N_NODES] = tmp[255];
}

__global__ void scan_fix(int* __restrict__ start, const int* __restrict__ boff) {
    const int t = threadIdx.x, i = blockIdx.x * 256 + t;
    if (i < N_NODES) start[i] += boff[blockIdx.x];
}

__global__ void scatter_kernel(const int* __restrict__ eidx, const int* __restrict__ start,
                               const int* __restrict__ pos0, int4* __restrict__ srt) {
    int e = blockIdx.x * 256 + threadIdx.x;
    if (e < N_EDGES) {
        int r = eidx[e];
        int c = eidx[N_EDGES + e];
        int slot = start[c] + pos0[e];
        srt[slot] = make_int4(e, r, c, 0);
    }
}

// ---------------------------------------------------------------------------
// Main fused kernel: persistent blocks, LDS-resident weights (R6, confirmed),
// + register prefetch pipeline across tiles, + fused segmented accumulation
// into the outputs (replaces msg buffer + gather kernel).
// 256 blocks x 8 waves; each wave owns 25 contiguous sorted 16-edge tiles and
// a private 8 KB LDS slice. Only wave-local fences after the one staging
// barrier. Outputs must be zeroed before launch (atomic accumulate).
__global__ __launch_bounds__(512, 2)
void eq_main_sorted(const float* __restrict__ x_scalar, const float* __restrict__ x_rot,
                    const float* __restrict__ dist, const float* __restrict__ rot,
                    const unsigned short* __restrict__ W1R, const float* __restrict__ b1,
                    const unsigned short* __restrict__ W2R, const float* __restrict__ b2,
                    const int4* __restrict__ srt,
                    float* __restrict__ out_scalar, float* __restrict__ out_rot)
{
    __shared__ unsigned char SH[155648];
    unsigned char* W1L = SH;                         // 65536 B
    unsigned char* W2L = SH + 65536;                 // 24576 B

    const int tid  = threadIdx.x;                    // 0..511
    const int wave = tid >> 6, lane = tid & 63;
    unsigned char* tile = SH + 90112 + wave * 8192;  // wave-private 8 KB
    // per-wave tile sub-layout (time-shared):
    //  [0,8192)  stage-1 A tile (bf16, swizzled)        -- dead after GEMM1
    //  [0,4352)  H (bf16)                               -- dead after GEMM2
    //  [0,6400)  XO (fp32)                              -- dead after stage 4
    //  [6400,7424) rbL: 16 rows x 16 floats (written post-GEMM1, A dead)
    //  [7424,7488) cL : 16 ints
    float*          XOf = (float*)tile;
    float*          rbL = (float*)(tile + 6400);
    int*            cLs = (int*)(tile + 7424);
    unsigned short* H16 = (unsigned short*)tile;

    // ---- one-time: stage rearranged weights to LDS (linear copy) ----------
    {
        const uint4* g1 = (const uint4*)W1R;  uint4* l1 = (uint4*)W1L;
        #pragma unroll
        for (int i = 0; i < 8; ++i) l1[i * 512 + tid] = g1[i * 512 + tid];
        const uint4* g2 = (const uint4*)W2R;  uint4* l2 = (uint4*)W2L;
        #pragma unroll
        for (int i = 0; i < 3; ++i) l2[i * 512 + tid] = g2[i * 512 + tid];
    }
    __syncthreads();                                 // the ONLY block barrier

    const int eL = lane >> 2, p = lane & 3;
    const int lrow = lane & 15, quad = lane >> 4;

    const int g  = blockIdx.x * 8 + wave;            // global wave id
    int t0 = g * TPW, t1 = t0 + TPW;
    if (t1 > NTILES) t1 = NTILES;
    if (t0 >= t1) return;                            // no barriers after this

    // ---- prefetch machinery -----------------------------------------------
    // per tile, per thread: A-half 8xfloat4, B-half 8xfloat4, rot 4xfloat4.
    float4 cA[16], cRb4[4];
    int4 ercC, ercN;

    auto addr_sel = [&](const int4& er, const float*& baseA, const float*& baseB) {
        const int e = er.x, r = er.y, c = er.z;
        if (p == 0)      { baseA = x_scalar + (size_t)c * NSC;
                           baseB = x_rot    + (size_t)c * 64;      }
        else if (p == 1) { baseA = x_rot    + (size_t)c * 64 + 32;
                           baseB = x_scalar + (size_t)r * NSC;     }
        else if (p == 2) { baseA = x_rot    + (size_t)r * 64;
                           baseB = x_rot    + (size_t)r * 64 + 32; }
        else             { baseA = dist     + (size_t)e * 64;
                           baseB = dist     + (size_t)e * 64 + 32; }
        (void)0;
        return e;
    };

    #define ISSUE_PREFETCH(ER, PA, PR) do { \
        const float *bA_, *bB_; \
        const int e_ = addr_sel(ER, bA_, bB_); \
        const float4* rp_ = (const float4*)(rot + (size_t)e_ * 16); \
        _Pragma("unroll") \
        for (int i_ = 0; i_ < 4; ++i_) (PR)[i_] = rp_[i_]; \
        _Pragma("unroll") \
        for (int i_ = 0; i_ < 4; ++i_) { \
            (PA)[2*i_]     = ((const float4*)(bA_ + i_*8))[0]; \
            (PA)[2*i_ + 1] = ((const float4*)(bA_ + i_*8))[1]; \
            (PA)[8 + 2*i_] = ((const float4*)(bB_ + i_*8))[0]; \
            (PA)[9 + 2*i_] = ((const float4*)(bB_ + i_*8))[1]; \
        } \
    } while (0)

    // prologue: data for t0, erc for t0+1
    ercC = srt[t0 * 16 + eL];
    ISSUE_PREFETCH(ercC, cA, cRb4);
    {
        int tn = (t0 + 1 < t1) ? t0 + 1 : t0;
        ercN = srt[tn * 16 + eL];
    }

    // segmented-accumulation state (columns owned by lanes 0..47)
    const int c0 = 2 * lane;                         // column pair base
    float acc0 = 0.f, acc1 = 0.f;
    int prevc = -1;

    for (int t = t0; t < t1; ++t) {
        // ---------- stage 1: build 16x256 bf16 A tile from prefetched regs --
        {
            float rb[16];
            #pragma unroll
            for (int i = 0; i < 4; ++i) ((float4*)rb)[i] = cRb4[i];
            const bool rotA = (p == 1) || (p == 2);
            const bool rotB = (p == 0) || (p == 2);
            #pragma unroll
            for (int i = 0; i < 8; ++i) {
                const bool isrot = (i < 4) ? rotA : rotB;
                float4 v0 = cA[2 * i], v1 = cA[2 * i + 1];
                float x[8] = { v0.x, v0.y, v0.z, v0.w, v1.x, v1.y, v1.z, v1.w };
                u16x8 tt;
                #pragma unroll
                for (int k = 0; k < 4; ++k) {
                    float a0 = x[2 * k], a1 = x[2 * k + 1];
                    float r0 = a0 * rb[4 * k]     + a1 * rb[4 * k + 1];
                    float r1 = a0 * rb[4 * k + 2] + a1 * rb[4 * k + 3];
                    tt[2 * k]     = f2bf(isrot ? r0 : a0);
                    tt[2 * k + 1] = f2bf(isrot ? r1 : a1);
                }
                const int ci = p * 8 + i;
                *(u16x8*)&tile[(eL << 9) + ((ci * 16) ^ ((eL & 7) << 4))] = tt;
            }
        }

        // ---------- issue prefetch for t+1 (overlaps GEMMs below) -----------
        float4 nA[16], nRb4[4];
        ISSUE_PREFETCH(ercN, nA, nRb4);
        int4 ercN2;
        {
            int tn2 = (t + 2 < t1) ? t + 2 : t;
            ercN2 = srt[tn2 * 16 + eL];
        }

        WAVE_SYNC();                                 // A-tile writes visible

        // ---------- stage 2: GEMM1  msg(16x256) @ W1(256x128) ---------------
        f32x4 acc[8];
        #pragma unroll
        for (int j = 0; j < 8; ++j) acc[j] = (f32x4){0.f, 0.f, 0.f, 0.f};
        #pragma unroll
        for (int kk = 0; kk < 8; ++kk) {
            bf16x8 a = *(const bf16x8*)&tile[(lrow << 9) +
                                             ((kk * 64 + quad * 16) ^ ((lrow & 7) << 4))];
            const unsigned char* wb = W1L + ((kk * 4 + quad) * 128) * 16;
            #pragma unroll
            for (int j = 0; j < 8; ++j) {
                bf16x8 b = *(const bf16x8*)(wb + (j * 16 + lrow) * 16);
                acc[j] = __builtin_amdgcn_mfma_f32_16x16x32_bf16(a, b, acc[j], 0, 0, 0);
            }
        }
        WAVE_SYNC();                                 // A reads done -> reuse buffer

        // H write + stash rb/c for stage 4 (A region dead now)
        #pragma unroll
        for (int j = 0; j < 8; ++j) {
            const int n = j * 16 + lrow;
            const float bv = b1[n];
            #pragma unroll
            for (int rr = 0; rr < 4; ++rr) {
                const int m = quad * 4 + rr;
                float v = acc[j][rr] + bv;
                float hv = v / (1.0f + __expf(-v));
                H16[m * LDH + n] = f2bf(hv);
            }
        }
        {
            float4 w = (p == 0) ? cRb4[0] : (p == 1) ? cRb4[1]
                     : (p == 2) ? cRb4[2] : cRb4[3];
            *(float4*)&rbL[eL * 16 + 4 * p] = w;     // row eL, quarter p
            if (p == 0) cLs[eL] = ercC.z;
        }
        WAVE_SYNC();                                 // H/rbL/cL visible

        // ---------- stage 3: GEMM2  h(16x128) @ W2(128x96) ------------------
        f32x4 acc2[6];
        #pragma unroll
        for (int j = 0; j < 6; ++j) acc2[j] = (f32x4){0.f, 0.f, 0.f, 0.f};
        #pragma unroll
        for (int kk = 0; kk < 4; ++kk) {
            bf16x8 a = *(const bf16x8*)&H16[lrow * LDH + kk * 32 + quad * 8];
            const unsigned char* wb = W2L + ((kk * 4 + quad) * 96) * 16;
            #pragma unroll
            for (int j = 0; j < 6; ++j) {
                bf16x8 b = *(const bf16x8*)(wb + (j * 16 + lrow) * 16);
                acc2[j] = __builtin_amdgcn_mfma_f32_16x16x32_bf16(a, b, acc2[j], 0, 0, 0);
            }
        }
        WAVE_SYNC();                                 // H reads done -> XO write ok

        #pragma unroll
        for (int j = 0; j < 6; ++j) {
            const int n = j * 16 + lrow;
            const float bv = b2[n];
            #pragma unroll
            for (int rr = 0; rr < 4; ++rr) {
                const int m = quad * 4 + rr;
                XOf[m * LDXO + n] = acc2[j][rr] + bv;
            }
        }
        WAVE_SYNC();                                 // XO visible

        // ---------- stage 4: segmented accumulate into outputs --------------
        if (lane < 48) {
            #pragma unroll
            for (int rI = 0; rI < 16; ++rI) {
                float2 v = *(const float2*)&XOf[rI * LDXO + c0];
                float v0 = v.x, v1 = v.y;
                if (c0 >= NSC) {
                    const int k = ((c0 - NSC) >> 1) & 3;
                    const float4 R = *(const float4*)&rbL[rI * 16 + 4 * k];
                    float a0 = v0, a1 = v1;
                    v0 = a0 * R.x + a1 * R.z;
                    v1 = a0 * R.y + a1 * R.w;
                }
                int cr = cLs[rI];
                if (cr != prevc) {                   // wave-uniform branch
                    if (prevc >= 0) {
                        float* bp = (c0 < NSC)
                            ? (out_scalar + (size_t)prevc * NSC + c0)
                            : (out_rot    + (size_t)prevc * 64 + (c0 - NSC));
                        atomicAdd(bp,     acc0);
                        atomicAdd(bp + 1, acc1);
                    }
                    acc0 = 0.f; acc1 = 0.f; prevc = cr;
                }
                acc0 += v0; acc1 += v1;
            }
        }
        WAVE_SYNC();                                 // XO/rbL/cL reads done

        // ---------- rotate pipeline registers -------------------------------
        #pragma unroll
        for (int i = 0; i < 16; ++i) cA[i] = nA[i];
        #pragma unroll
        for (int i = 0; i < 4; ++i) cRb4[i] = nRb4[i];
        ercC = ercN; ercN = ercN2;
    }

    // final segment flush
    if (lane < 48 && prevc >= 0) {
        float* bp = (c0 < NSC)
            ? (out_scalar + (size_t)prevc * NSC + c0)
            : (out_rot    + (size_t)prevc * 64 + (c0 - NSC));
        atomicAdd(bp,     acc0);
        atomicAdd(bp + 1, acc1);
    }
    #undef ISSUE_PREFETCH
}

// ---------------------------------------------------------------------------
// Fallback (atomic scatter) kernel — only used when the workspace is too
// small for the sorted path. Rearranged weight layout (R6-verified).
__global__ __launch_bounds__(256, 2)
void eq_main_atomic(const float* __restrict__ x_scalar, const float* __restrict__ x_rot,
                    const int* __restrict__ eidx, const float* __restrict__ dist,
                    const float* __restrict__ rot,
                    const unsigned short* __restrict__ W1R, const float* __restrict__ b1,
                    const unsigned short* __restrict__ W2R, const float* __restrict__ b2,
                    float* __restrict__ out_scalar, float* __restrict__ out_rot)
{
    __shared__ union { unsigned char B[64 * 512]; float XO[64 * LDXO]; } uA;
    __shared__ unsigned short H[64 * LDH];
    __shared__ int colidx[64];

    const int tid = threadIdx.x;
    const int e0  = blockIdx.x * 64;

    {
        const int eL = tid >> 2, p = tid & 3;
        const int e  = e0 + eL;
        if (e < N_EDGES) {
            const int r = eidx[e];
            const int c = eidx[N_EDGES + e];
            if (p == 0) colidx[eL] = c;
            float rb[16];
            {
                const float4* rp = (const float4*)(rot + (size_t)e * 16);
                #pragma unroll
                for (int i = 0; i < 4; ++i) ((float4*)rb)[i] = rp[i];
            }
            const float *baseA, *baseB; bool rotA, rotB;
            if (p == 0)      { baseA = x_scalar + (size_t)c * NSC;     rotA = false;
                               baseB = x_rot    + (size_t)c * 64;      rotB = true;  }
            else if (p == 1) { baseA = x_rot    + (size_t)c * 64 + 32; rotA = true;
                               baseB = x_scalar + (size_t)r * NSC;     rotB = false; }
            else if (p == 2) { baseA = x_rot    + (size_t)r * 64;      rotA = true;
                               baseB = x_rot    + (size_t)r * 64 + 32; rotB = true;  }
            else             { baseA = dist     + (size_t)e * 64;      rotA = false;
                               baseB = dist     + (size_t)e * 64 + 32; rotB = false; }
            #pragma unroll
            for (int i = 0; i < 8; ++i) {
                const float* src  = (i < 4) ? (baseA + i * 8) : (baseB + (i - 4) * 8);
                const bool  isrot = (i < 4) ? rotA : rotB;
                float4 v0 = ((const float4*)src)[0], v1 = ((const float4*)src)[1];
                float x[8] = { v0.x, v0.y, v0.z, v0.w, v1.x, v1.y, v1.z, v1.w };
                u16x8 tt;
                #pragma unroll
                for (int k = 0; k < 4; ++k) {
                    float a0 = x[2 * k], a1 = x[2 * k + 1];
                    float r0 = a0 * rb[4 * k]     + a1 * rb[4 * k + 1];
                    float r1 = a0 * rb[4 * k + 2] + a1 * rb[4 * k + 3];
                    tt[2 * k]     = f2bf(isrot ? r0 : a0);
                    tt[2 * k + 1] = f2bf(isrot ? r1 : a1);
                }
                const int ci = p * 8 + i;
                *(u16x8*)&uA.B[(eL << 9) + ((ci * 16) ^ ((eL & 7) << 4))] = tt;
            }
        }
    }
    __syncthreads();

    const int lane = tid & 63, wave = tid >> 6;
    const int lrow = lane & 15, quad = lane >> 4;
    const int m0 = wave * 16;

    {
        f32x4 acc[8];
        #pragma unroll
        for (int j = 0; j < 8; ++j) acc[j] = (f32x4){0.f, 0.f, 0.f, 0.f};
        #pragma unroll
        for (int kk = 0; kk < 8; ++kk) {
            bf16x8 a = *(const bf16x8*)&uA.B[((m0 + lrow) << 9) +
                                             ((kk * 64 + quad * 16) ^ ((lrow & 7) << 4))];
            const unsigned short* wb = W1R + (size_t)(kk * 4 + quad) * 1024;
            #pragma unroll
            for (int j = 0; j < 8; ++j) {
                bf16x8 b = *(const bf16x8*)(wb + (j * 16 + lrow) * 8);
                acc[j] = __builtin_amdgcn_mfma_f32_16x16x32_bf16(a, b, acc[j], 0, 0, 0);
            }
        }
        __syncthreads();
        #pragma unroll
        for (int j = 0; j < 8; ++j) {
            const int n = j * 16 + lrow;
            const float bv = b1[n];
            #pragma unroll
            for (int rr = 0; rr < 4; ++rr) {
                const int m = m0 + quad * 4 + rr;
                float v = acc[j][rr] + bv;
                float hv = v / (1.0f + __expf(-v));
                H[m * LDH + n] = f2bf(hv);
            }
        }
    }
    __syncthreads();

    {
        f32x4 acc2[6];
        #pragma unroll
        for (int j = 0; j < 6; ++j) acc2[j] = (f32x4){0.f, 0.f, 0.f, 0.f};
        #pragma unroll
        for (int kk = 0; kk < 4; ++kk) {
            bf16x8 a = *(const bf16x8*)&H[(m0 + lrow) * LDH + kk * 32 + quad * 8];
            const unsigned short* wb = W2R + (size_t)(kk * 4 + quad) * 768;
            #pragma unroll
            for (int j = 0; j < 6; ++j) {
                bf16x8 b = *(const bf16x8*)(wb + (j * 16 + lrow) * 8);
                acc2[j] = __builtin_amdgcn_mfma_f32_16x16x32_bf16(a, b, acc2[j], 0, 0, 0);
            }
        }
        __syncthreads();
        #pragma unroll
        for (int j = 0; j < 6; ++j) {
            const int n = j * 16 + lrow;
            const float bv = b2[n];
            #pragma unroll
            for (int rr = 0; rr < 4; ++rr) {
                const int m = m0 + quad * 4 + rr;
                float v = acc2[j][rr] + bv;
                if (j < 2) {
                    if (e0 + m < N_EDGES)
                        atomicAdd(&out_scalar[(size_t)colidx[m] * NSC + n], v);
                } else {
                    uA.XO[m * LDXO + (n - NSC)] = v;
                }
            }
        }
    }
    __syncthreads();

    {
        const int eL = tid >> 2, p = tid & 3;
        const int e  = e0 + eL;
        if (e < N_EDGES) {
            float rb[16];
            {
                const float4* rp = (const float4*)(rot + (size_t)e * 16);
                #pragma unroll
                for (int i = 0; i < 4; ++i) ((float4*)rb)[i] = rp[i];
            }
            const int c = colidx[eL];
            const float* xo = &uA.XO[eL * LDXO];
            float* outp = out_rot + (size_t)c * 64;
            #pragma unroll
            for (int jj = 0; jj < 2; ++jj) {
                const int j = 2 * p + jj;
                #pragma unroll
                for (int k = 0; k < 4; ++k) {
                    float a0 = xo[j * 8 + k * 2], a1 = xo[j * 8 + k * 2 + 1];
                    atomicAdd(&outp[j * 8 + k * 2 + 0], a0 * rb[4 * k + 0] + a1 * rb[4 * k + 2]);
                    atomicAdd(&outp[j * 8 + k * 2 + 1], a0 * rb[4 * k + 1] + a1 * rb[4 * k + 3]);
                }
            }
        }
    }
}

// ---------------------------------------------------------------------------
extern "C" void kernel_launch(void* const* d_in, const int* in_sizes, int n_in,
                              void* d_out, int out_size, void* d_ws, size_t ws_size,
                              hipStream_t stream) {
    const float* x_scalar = (const float*)d_in[0];
    const float* x_rot    = (const float*)d_in[1];
    const int*   eidx     = (const int*)d_in[2];
    const float* dist     = (const float*)d_in[3];
    const float* rot      = (const float*)d_in[4];
    const float* W1       = (const float*)d_in[5];
    const float* b1       = (const float*)d_in[6];
    const float* W2       = (const float*)d_in[7];
    const float* b2       = (const float*)d_in[8];
    float* out        = (float*)d_out;
    float* out_rot    = out + (size_t)N_NODES * NSC;

    // workspace bump allocator (256B aligned)
    uintptr_t base = (uintptr_t)d_ws;
    auto alloc = [&](size_t bytes) {
        uintptr_t p = base; base += (bytes + 255) & ~(size_t)255; return p;
    };
    unsigned short* W1R  = (unsigned short*)alloc(256 * 128 * 2);
    unsigned short* W2R  = (unsigned short*)alloc(128 * 96 * 2);
    int*            cnt  = (int*)alloc(N_NODES * 4);
    int*            start= (int*)alloc((N_NODES + 1) * 4);
    int*            bsum = (int*)alloc(NBLK * 4);
    int*            boff = (int*)alloc(NBLK * 4);
    int*            pos0 = (int*)alloc((size_t)N_EDGES * 4);
    int4*           srt  = (int4*)alloc((size_t)N_EDGES * 16);
    const size_t needed = base - (uintptr_t)d_ws;

    prep_weights<<<128, 256, 0, stream>>>(W1, W2, W1R, W2R);
    hipMemsetAsync(d_out, 0, (size_t)out_size * sizeof(float), stream);

    if (ws_size >= needed) {
        hipMemsetAsync(cnt, 0, N_NODES * 4, stream);
        rank0_kernel<<<N_EDGES / 256, 256, 0, stream>>>(eidx, cnt, pos0);
        scan_block<<<NBLK, 256, 0, stream>>>(cnt, start, bsum);
        scan_top<<<1, 256, 0, stream>>>(bsum, boff, start);
        scan_fix<<<NBLK, 256, 0, stream>>>(start, boff);
        scatter_kernel<<<N_EDGES / 256, 256, 0, stream>>>(eidx, start, pos0, srt);
        eq_main_sorted<<<256, 512, 0, stream>>>(
            x_scalar, x_rot, dist, rot, W1R, b1, W2R, b2, srt, out, out_rot);
    } else {
        // fallback: atomic scatter
        eq_main_atomic<<<N_EDGES / 64, 256, 0, stream>>>(
            x_scalar, x_rot, eidx, dist, rot, W1R, b1, W2R, b2,
            out, out_rot);
    }
}